// Round 6
// baseline (290.854 us; speedup 1.0000x reference)
//
#include <hip/hip_runtime.h>
#include <math.h>

#define B_  64
#define L_  48
#define E_  300
#define F0_ 300
#define NEGP (-1e30f)
#define XROW 320      // X row stride in halves (640B, 16B aligned)
#define RS  312       // k2 r-tile LDS row stride (halves)

typedef __attribute__((ext_vector_type(8))) _Float16 half8;
typedef __attribute__((ext_vector_type(8))) short   short8;
typedef __attribute__((ext_vector_type(4))) float   float4v;

// -------- workspace layout (float offsets) --------
// r1    : 0        .. 921600      (B*L*E) fp32
// r2    : 921600   .. 1843200
// s1p   : 1843200  .. 4608000     (B*3*48*300) pre-tanh partial max over j per j-tile
//   X   : 1843200  .. 2826240     [pre-k2 alias] 6144x320 fp16 gathered embeddings
//   Bc  : 2826240  .. 2972160     [pre-k2 alias] 30x19x64x8 fp16 conv-W frags
// s2p   : 4608000  .. 7372800
// s1    : 7372800  .. 8294400
// s2    : 8294400  .. 9216000
// Bp2   : 9254400  .. 9351680     95x4x64x8 fp16 fc0_w frags (per-lane order)
// fc1wT : 9351680  .. 9442880     600x304 fp16 transposed fc1_w

// ---------------- fused prep kernel ----------------
__global__ __launch_bounds__(256) void kp_all(
    const int* __restrict__ q1, const int* __restrict__ q2,
    const float* __restrict__ emb, const float* __restrict__ conv_w,
    const float* __restrict__ fc0w, const float* __restrict__ fc1w,
    _Float16* __restrict__ Bp2, _Float16* __restrict__ Bc,
    _Float16* __restrict__ fc1wT, _Float16* __restrict__ X)
{
    int u = blockIdx.x * 256 + threadIdx.x;
    if (u < 24320) {
        // Bp2[m][nt][lane][8]; m=nc*19+kc; f=nc*64+nt*16+(lane&15); k=kc*32+(lane>>4)*8+j
        int m = u >> 8, rest = u & 255;
        int nt = rest >> 6, lane = rest & 63;
        int f = (m / 19) * 64 + nt * 16 + (lane & 15);
        int kb = (m % 19) * 32 + ((lane >> 4) << 3);
        half8 hv;
#pragma unroll
        for (int j = 0; j < 8; ++j) {
            int k = kb + j;
            float v = 0.f;
            if (f < 300) {
                if (k < 300) v = fc0w[f * 600 + k];
                else if (k >= 304 && k < 604) v = fc0w[f * 600 + k - 4];
            }
            hv[j] = (_Float16)v;
        }
        *reinterpret_cast<half8*>(Bp2 + (long)u * 8) = hv;
    } else if (u < 60800) {
        // Bc[m][ntg][lane][8]; k=m/10; kk=(m%10)*32+(lane>>4)*8+j; o=ntg*16+(lane&15)
        int v = u - 24320;
        int m = v / 1216, rest = v - m * 1216;
        int ntg = rest >> 6, lane = rest & 63;
        int o = ntg * 16 + (lane & 15);
        int kkb = (m % 10) * 32 + ((lane >> 4) << 3);
        int k = m / 10;
        half8 hv;
#pragma unroll
        for (int j = 0; j < 8; ++j) {
            int kk = kkb + j;
            float val = 0.f;
            if (o < 300 && kk < 300) val = conv_w[(o * 300 + kk) * 3 + k];
            hv[j] = (_Float16)val;
        }
        *reinterpret_cast<half8*>(Bc + (long)v * 8) = hv;
    } else if (u < 83600) {
        // fc1wT[e][g] = fc1w[g][e], fp16, 304-padded
        int v = u - 60800;
        int e = v / 38;
        int g8 = (v - e * 38) * 8;
        half8 hv;
#pragma unroll
        for (int j = 0; j < 8; ++j) {
            int g = g8 + j;
            hv[j] = (_Float16)((g < 300) ? fc1w[g * 600 + e] : 0.f);
        }
        *reinterpret_cast<half8*>(fc1wT + (long)e * 304 + g8) = hv;
    } else if (u < 329360) {
        // X[(s,b,l)][i] = fp16(emb[q,i]), 320-padded
        int v = u - 83600;
        int g = v / 40;
        int e8 = (v - g * 40) * 8;
        int s = g / 3072;
        int rem = g - s * 3072;
        long row = (long)((s ? q2 : q1)[rem]) * 300;
        half8 hv;
        if (e8 + 7 < 300) {
            float4 a = *reinterpret_cast<const float4*>(emb + row + e8);
            float4 c = *reinterpret_cast<const float4*>(emb + row + e8 + 4);
            hv[0] = (_Float16)a.x; hv[1] = (_Float16)a.y; hv[2] = (_Float16)a.z; hv[3] = (_Float16)a.w;
            hv[4] = (_Float16)c.x; hv[5] = (_Float16)c.y; hv[6] = (_Float16)c.z; hv[7] = (_Float16)c.w;
        } else {
#pragma unroll
            for (int j = 0; j < 8; ++j) {
                int i = e8 + j;
                hv[j] = (_Float16)((i < 300) ? emb[row + i] : 0.f);
            }
        }
        *reinterpret_cast<half8*>(X + (long)g * XROW + e8) = hv;
    }
}

// ---------------- conv GEMM: one wave per (m-tile, ntg-pair) ----------------
// 3840 wave-jobs = 960 blocks x 4 waves -> ~47% occupancy; barrier-free, no LDS.
__global__ __launch_bounds__(256, 4) void kc_conv(
    const _Float16* __restrict__ X, const _Float16* __restrict__ Bc,
    const float* __restrict__ conv_b, float* __restrict__ r1, float* __restrict__ r2)
{
    int wid = blockIdx.x * 4 + (threadIdx.x >> 6);   // 0..3839
    int lane = threadIdx.x & 63;
    int mt = wid / 10;            // m-tile 0..383
    int pr = wid - mt * 10;       // ntg-pair 0..9
    int ntg0 = pr * 2;
    bool two = (ntg0 + 1 < 19);
    int row0 = mt * 16;
    int q = lane >> 4, jcol = lane & 15;
    int grow = row0 + jcol;       // this lane's A row
    int l = grow % 48;

    auto zero8 = []() { half8 z; for (int e = 0; e < 8; ++e) z[e] = (_Float16)0.f; return z; };
    auto loadA = [&](int m) -> half8 {
        int k = m / 10, kk0 = (m - k * 10) * 32;
        int srcl = l + k - 1;
        if (srcl >= 0 && srcl < 48)
            return *reinterpret_cast<const half8*>(X + (long)(grow + k - 1) * XROW + kk0 + q * 8);
        return zero8();
    };
    auto loadB = [&](int m, int ntg) -> half8 {
        return *reinterpret_cast<const half8*>(Bc + ((long)m * 19 + ntg) * 512 + lane * 8);
    };

    float4v acc0 = (float4v){0.f, 0.f, 0.f, 0.f};
    float4v acc1 = (float4v){0.f, 0.f, 0.f, 0.f};

    half8 a_c  = loadA(0);
    half8 b0_c = loadB(0, ntg0);
    half8 b1_c = two ? loadB(0, ntg0 + 1) : b0_c;

    for (int m = 0; m < 30; ++m) {
        half8 a_n, b0_n, b1_n;
        if (m < 29) {
            a_n  = loadA(m + 1);
            b0_n = loadB(m + 1, ntg0);
            b1_n = two ? loadB(m + 1, ntg0 + 1) : b0_n;
        } else { a_n = a_c; b0_n = b0_c; b1_n = b1_c; }
        acc0 = __builtin_amdgcn_mfma_f32_16x16x32_f16(a_c, b0_c, acc0, 0, 0, 0);
        if (two)
            acc1 = __builtin_amdgcn_mfma_f32_16x16x32_f16(a_c, b1_c, acc1, 0, 0, 0);
        a_c = a_n; b0_c = b0_n; b1_c = b1_n;
    }

    // epilogue: row = q*4+r, col = ntg*16+jcol
#pragma unroll
    for (int t = 0; t < 2; ++t) {
        if (t == 1 && !two) break;
        int n = (ntg0 + t) * 16 + jcol;
        if (n >= 300) continue;
        float bias = conv_b[n];
        const float4v& a = t ? acc1 : acc0;
#pragma unroll
        for (int r = 0; r < 4; ++r) {
            int g = row0 + q * 4 + r;
            int s = g / 3072;
            int rem = g - s * 3072;
            float* rout = s ? r2 : r1;
            rout[(long)rem * 300 + n] = tanhf(a[r] + bias);
        }
    }
}

// ---------------------------------------------------------------------------
// K2: barrier-free K-loop. Block = (b, it, jt, nc): 16i x 16j pairs, 64 f.
// ---------------------------------------------------------------------------
__global__ __launch_bounds__(256, 3) void k2_joint(
    const float* __restrict__ r1, const float* __restrict__ r2,
    const int* __restrict__ q1_len, const int* __restrict__ q2_len,
    const _Float16* __restrict__ Bp2,
    float* __restrict__ s1p, float* __restrict__ s2p)
{
    int x = blockIdx.x;               // 0..44
    int tile = x / 5, nc = x - tile * 5;
    int it = tile / 3, jt = tile - it * 3;
    int b = blockIdx.y;
    int tid = threadIdx.x;
    int q1l = q1_len[b], q2l = q2_len[b];
    long base1 = ((long)(b * 3 + jt) * 48 + it * 16) * 300;
    long base2 = ((long)(b * 3 + it) * 48 + jt * 16) * 300;
    bool active = (it * 16 < q1l) && (jt * 16 < q2l);
    if (!active) {
        for (int idx = tid; idx < 2048; idx += 256) {
            int side = idx >> 10;
            int rest = idx & 1023;
            int row = rest >> 6;
            int f = nc * 64 + (rest & 63);
            if (f < 300) (side ? s2p + base2 : s1p + base1)[row * 300 + f] = NEGP;
        }
        return;
    }

    __shared__ __align__(16) unsigned char smraw[16 * RS * 2 * 2];  // 19968 B
    _Float16* r1h = (_Float16*)smraw;
    _Float16* r2h = r1h + 16 * RS;
    float* red = (float*)smraw;       // union, epilogue only (64x68)

    {
        const float* r1base = r1 + ((long)(b * 48) + it * 16) * 300;
        const float* r2base = r2 + ((long)(b * 48) + jt * 16) * 300;
        for (int u = tid; u < 1200; u += 256) {
            int row = u / 75;
            int e4 = (u - row * 75) * 4;
            float4 v1 = *reinterpret_cast<const float4*>(r1base + row * 300 + e4);
            float4 v2 = *reinterpret_cast<const float4*>(r2base + row * 300 + e4);
            _Float16* d1 = r1h + row * RS + e4;
            _Float16* d2 = r2h + row * RS + e4;
            d1[0] = (_Float16)v1.x; d1[1] = (_Float16)v1.y; d1[2] = (_Float16)v1.z; d1[3] = (_Float16)v1.w;
            d2[0] = (_Float16)v2.x; d2[1] = (_Float16)v2.y; d2[2] = (_Float16)v2.z; d2[3] = (_Float16)v2.w;
        }
        for (int u = tid; u < 2 * 16 * (RS - 300); u += 256) {
            int half = u / (16 * (RS - 300));
            int rest = u - half * 16 * (RS - 300);
            int row = rest / (RS - 300);
            int e = 300 + rest - row * (RS - 300);
            (half ? r2h : r1h)[row * RS + e] = (_Float16)0.f;
        }
    }
    __syncthreads();

    int w    = tid >> 6;
    int lane = tid & 63;
    int q    = lane >> 4;
    int jcol = lane & 15;

    float4v acc[4][4];
#pragma unroll
    for (int mt = 0; mt < 4; ++mt)
#pragma unroll
        for (int nt = 0; nt < 4; ++nt) acc[mt][nt] = (float4v){0.f, 0.f, 0.f, 0.f};

    const _Float16* bbase = Bp2 + (long)(nc * 19) * 2048;
    half8 b0 = *reinterpret_cast<const half8*>(bbase + lane * 8);
    half8 b1 = *reinterpret_cast<const half8*>(bbase + 512 + lane * 8);
    half8 b2 = *reinterpret_cast<const half8*>(bbase + 1024 + lane * 8);
    half8 b3 = *reinterpret_cast<const half8*>(bbase + 1536 + lane * 8);

    for (int kc = 0; kc < 19; ++kc) {
        half8 n0, n1, n2, n3;
        if (kc < 18) {
            const _Float16* nb = bbase + (long)(kc + 1) * 2048;
            n0 = *reinterpret_cast<const half8*>(nb + lane * 8);
            n1 = *reinterpret_cast<const half8*>(nb + 512 + lane * 8);
            n2 = *reinterpret_cast<const half8*>(nb + 1024 + lane * 8);
            n3 = *reinterpret_cast<const half8*>(nb + 1536 + lane * 8);
        } else { n0 = b0; n1 = b1; n2 = b2; n3 = b3; }

        int k0q = kc * 32 + q * 8;
        int koff = (k0q < 304) ? k0q : (k0q - 304);
        const half8 rv2 = *reinterpret_cast<const half8*>(r2h + jcol * RS + koff);
        half8 afr[4];
#pragma unroll
        for (int mt = 0; mt < 4; ++mt) {
            const half8 rv1 = *reinterpret_cast<const half8*>(r1h + (w * 4 + mt) * RS + koff);
            if (k0q < 304) {
                half8 dsub = rv1 - rv2;
                short8 s;
                __builtin_memcpy(&s, &dsub, 16);
                s &= (short)0x7FFF;
                __builtin_memcpy(&afr[mt], &s, 16);
            } else {
                afr[mt] = rv1 * rv2;
            }
        }
#pragma unroll
        for (int mt = 0; mt < 4; ++mt) {
            acc[mt][0] = __builtin_amdgcn_mfma_f32_16x16x32_f16(afr[mt], b0, acc[mt][0], 0, 0, 0);
            acc[mt][1] = __builtin_amdgcn_mfma_f32_16x16x32_f16(afr[mt], b1, acc[mt][1], 0, 0, 0);
            acc[mt][2] = __builtin_amdgcn_mfma_f32_16x16x32_f16(afr[mt], b2, acc[mt][2], 0, 0, 0);
            acc[mt][3] = __builtin_amdgcn_mfma_f32_16x16x32_f16(afr[mt], b3, acc[mt][3], 0, 0, 0);
        }
        b0 = n0; b1 = n1; b2 = n2; b3 = n3;
    }

    // ---- s1: max over valid j ----
#pragma unroll
    for (int mt = 0; mt < 4; ++mt) {
        int i_l = w * 4 + mt;
#pragma unroll
        for (int nt = 0; nt < 4; ++nt) {
            float mx = NEGP;
#pragma unroll
            for (int r = 0; r < 4; ++r) {
                int j = q * 4 + r;
                if (jt * 16 + j < q2l) mx = fmaxf(mx, acc[mt][nt][r]);
            }
            mx = fmaxf(mx, __shfl_xor(mx, 16));
            mx = fmaxf(mx, __shfl_xor(mx, 32));
            int f = nc * 64 + nt * 16 + jcol;
            if (q == 0 && f < 300) s1p[base1 + i_l * 300 + f] = mx;
        }
    }

    // ---- s2: max over valid i, cross-wave via LDS ----
    __syncthreads();
#pragma unroll
    for (int nt = 0; nt < 4; ++nt) {
#pragma unroll
        for (int r = 0; r < 4; ++r) {
            float mx = NEGP;
#pragma unroll
            for (int mt = 0; mt < 4; ++mt) {
                int i = it * 16 + w * 4 + mt;
                if (i < q1l) mx = fmaxf(mx, acc[mt][nt][r]);
            }
            red[((w * 16) + q * 4 + r) * 68 + nt * 16 + jcol] = mx;
        }
    }
    __syncthreads();
    for (int vv = tid; vv < 1024; vv += 256) {
        int j = vv >> 6;
        int fcol = vv & 63;
        float mx = red[j * 68 + fcol];
        mx = fmaxf(mx, red[(16 + j) * 68 + fcol]);
        mx = fmaxf(mx, red[(32 + j) * 68 + fcol]);
        mx = fmaxf(mx, red[(48 + j) * 68 + fcol]);
        int f = nc * 64 + fcol;
        if (f < 300) s2p[base2 + (long)j * 300 + f] = mx;
    }
}

// K3: s = tanh(bias + max over 3 tile-partials)
__global__ void k3_combine(const float* __restrict__ s1p, const float* __restrict__ s2p,
                           const float* __restrict__ fc0b,
                           float* __restrict__ s1, float* __restrict__ s2)
{
    int idx = blockIdx.x * 256 + threadIdx.x;
    if (idx >= 64 * 48 * 300) return;
    int b = idx / 14400;
    int lf = idx - b * 14400;
    int f = lf % 300;
    long p = (long)b * 43200 + lf;
    float m1v = fmaxf(fmaxf(s1p[p], s1p[p + 14400]), s1p[p + 28800]);
    float m2v = fmaxf(fmaxf(s2p[p], s2p[p + 14400]), s2p[p + 28800]);
    float bia = fc0b[f];
    s1[idx] = tanhf(m1v + bia);
    s2[idx] = tanhf(m2v + bia);
}

// K45: fused attention pooling (both sides) + final MLP, one block per b
__global__ __launch_bounds__(256) void k45_mlp(
    const float* __restrict__ r1, const float* __restrict__ r2,
    const float* __restrict__ s1, const float* __restrict__ s2,
    const int* __restrict__ q1_len, const int* __restrict__ q2_len,
    const float* __restrict__ att_w, const float* __restrict__ att_b,
    const _Float16* __restrict__ fc1wT, const float* __restrict__ fc1b,
    const float* __restrict__ fc2w, const float* __restrict__ fc2b,
    float* __restrict__ out)
{
    int b = blockIdx.x;
    int tid = threadIdx.x;
    int w = tid >> 6, lane = tid & 63;
    __shared__ float lg[2][48];
    __shared__ float aL[2][48];
    __shared__ float hc[600];
    __shared__ float jl[304];

    // phase 1: logits. rows 0..95 = (side,l); wave w owns rows w*24..w*24+23
    for (int li = 0; li < 24; ++li) {
        int row = w * 24 + li;
        int side = row >= 48;
        int l = row - side * 48;
        const float* r = (side ? r2 : r1) + ((long)b * 48 + l) * 300;
        const float* s = (side ? s2 : s1) + ((long)b * 48 + l) * 300;
        float acc = 0.f;
        for (int d = lane; d < 600; d += 64) {
            float v = (d < 300) ? r[d] : s[d - 300];
            acc += v * att_w[d];
        }
#pragma unroll
        for (int off = 32; off >= 1; off >>= 1) acc += __shfl_xor(acc, off);
        if (lane == 0) lg[side][l] = acc + att_b[0];
    }
    __syncthreads();
    // phase 2: softmax (wave 0 = side 0, wave 1 = side 1)
    if (tid < 128) {
        int side = tid >> 6;
        int len = (side ? q2_len : q1_len)[b];
        float lo = (lane < 48) ? lg[side][lane] : NEGP;
        float ml = (lane < len) ? lo : NEGP;
        float mx = ml;
#pragma unroll
        for (int off = 32; off >= 1; off >>= 1) mx = fmaxf(mx, __shfl_xor(mx, off));
        float ex = (lane < len) ? __expf(lo - mx) : 0.f;
        float sm = ex;
#pragma unroll
        for (int off = 32; off >= 1; off >>= 1) sm += __shfl_xor(sm, off);
        if (lane < 48) aL[side][lane] = ex / sm;
    }
    __syncthreads();
    // phase 3: h = concat(h1,h2) in LDS
    for (int u = tid; u < 600; u += 256) {
        int side = u >= 300;
        int f = u - side * 300;
        const float* s = (side ? s2 : s1) + (long)b * 48 * 300;
        float acc = 0.f;
        for (int l = 0; l < 48; ++l) acc += aL[side][l] * s[(long)l * 300 + f];
        hc[u] = acc;
    }
    __syncthreads();
    // phase 4: fc1 + tanh
    for (int g = tid; g < 304; g += 256) {
        float acc = (g < 300) ? fc1b[g] : 0.f;
#pragma unroll 8
        for (int e = 0; e < 600; ++e)
            acc += hc[e] * (float)fc1wT[(long)e * 304 + g];
        jl[g] = tanhf(acc);
    }
    __syncthreads();
    // phase 5: fc2
    if (tid < 128) {
        int o = tid >> 6;
        float acc = 0.f;
        for (int g = lane; g < 300; g += 64) acc += jl[g] * fc2w[o * 300 + g];
#pragma unroll
        for (int off = 32; off >= 1; off >>= 1) acc += __shfl_xor(acc, off);
        if (lane == 0) out[b * 2 + o] = acc + fc2b[o];
    }
}

extern "C" void kernel_launch(void* const* d_in, const int* in_sizes, int n_in,
                              void* d_out, int out_size, void* d_ws, size_t ws_size,
                              hipStream_t stream)
{
    const int*   q1     = (const int*)d_in[0];
    const int*   q2     = (const int*)d_in[1];
    const int*   q1_len = (const int*)d_in[2];
    const int*   q2_len = (const int*)d_in[3];
    const float* emb    = (const float*)d_in[4];
    const float* conv_w = (const float*)d_in[5];
    const float* conv_b = (const float*)d_in[6];
    const float* fc0_w  = (const float*)d_in[7];
    const float* fc0_b  = (const float*)d_in[8];
    const float* fc1_w  = (const float*)d_in[9];
    const float* fc1_b  = (const float*)d_in[10];
    const float* fc2_w  = (const float*)d_in[11];
    const float* fc2_b  = (const float*)d_in[12];
    const float* att_w  = (const float*)d_in[13];
    const float* att_b  = (const float*)d_in[14];

    float* ws  = (float*)d_ws;
    float* r1  = ws;
    float* r2  = ws + 921600;
    float* s1p = ws + 1843200;
    float* s2p = ws + 4608000;
    float* s1  = ws + 7372800;
    float* s2  = ws + 8294400;
    _Float16* X     = (_Float16*)(ws + 1843200);   // pre-k2 alias of s1p region
    _Float16* Bc    = (_Float16*)(ws + 2826240);   // pre-k2 alias of s1p region
    _Float16* Bp2   = (_Float16*)(ws + 9254400);
    _Float16* fc1wT = (_Float16*)(ws + 9351680);
    float* out = (float*)d_out;

    hipLaunchKernelGGL(kp_all, dim3(1287), dim3(256), 0, stream,
                       q1, q2, emb, conv_w, fc0_w, fc1_w, Bp2, Bc, fc1wT, X);
    hipLaunchKernelGGL(kc_conv, dim3(960), dim3(256), 0, stream,
                       X, Bc, conv_b, r1, r2);
    hipLaunchKernelGGL(k2_joint, dim3(45, 64), dim3(256), 0, stream,
                       r1, r2, q1_len, q2_len, Bp2, s1p, s2p);
    hipLaunchKernelGGL(k3_combine, dim3(3600), dim3(256), 0, stream,
                       s1p, s2p, fc0_b, s1, s2);
    hipLaunchKernelGGL(k45_mlp, dim3(64), dim3(256), 0, stream,
                       r1, r2, s1, s2, q1_len, q2_len, att_w, att_b,
                       fc1wT, fc1_b, fc2_w, fc2_b, out);
}

// Round 7
// 247.762 us; speedup vs baseline: 1.1739x; 1.1739x over previous
//
#include <hip/hip_runtime.h>
#include <math.h>

#define B_  64
#define L_  48
#define E_  300
#define F0_ 300
#define NEGP (-1e30f)
#define XROW 320      // X row stride in halves (640B, 16B aligned)
#define RS  312       // k2 r-tile LDS row stride (halves)

typedef __attribute__((ext_vector_type(8))) _Float16 half8;
typedef __attribute__((ext_vector_type(8))) short   short8;
typedef __attribute__((ext_vector_type(4))) float   float4v;

// -------- workspace layout (float offsets) --------
// r1    : 0        .. 921600      (B*L*E) fp32
// r2    : 921600   .. 1843200
// s1p   : 1843200  .. 4608000     (B*3*48*300) pre-tanh partial max over j per j-tile
//   X   : 1843200  .. 2826240     [pre-k2 alias] 6144x320 fp16 gathered embeddings
//   Bc  : 2826240  .. 2972160     [pre-k2 alias] 30x19x64x8 fp16 conv-W frags
// s2p   : 4608000  .. 7372800
// hcat  : 9216000  .. 9254400     64x600 pooled features
// Bp2   : 9254400  .. 9351680     95x4x64x8 fp16 fc0_w frags (per-lane order)
// jl    : 9351680  .. 9370880     64x300 fc1 activations

// ---------------- fused prep kernel ----------------
// sections (half8 units): Bp2 24320 | Bc 36480 | X 245760  -> total 306560
__global__ __launch_bounds__(256) void kp_all(
    const int* __restrict__ q1, const int* __restrict__ q2,
    const float* __restrict__ emb, const float* __restrict__ conv_w,
    const float* __restrict__ fc0w,
    _Float16* __restrict__ Bp2, _Float16* __restrict__ Bc,
    _Float16* __restrict__ X)
{
    int u = blockIdx.x * 256 + threadIdx.x;
    if (u < 24320) {
        // Bp2[m][nt][lane][8]; m=nc*19+kc; f=nc*64+nt*16+(lane&15); k=kc*32+(lane>>4)*8+j
        int m = u >> 8, rest = u & 255;
        int nt = rest >> 6, lane = rest & 63;
        int f = (m / 19) * 64 + nt * 16 + (lane & 15);
        int kb = (m % 19) * 32 + ((lane >> 4) << 3);
        half8 hv;
#pragma unroll
        for (int j = 0; j < 8; ++j) {
            int k = kb + j;
            float v = 0.f;
            if (f < 300) {
                if (k < 300) v = fc0w[f * 600 + k];
                else if (k >= 304 && k < 604) v = fc0w[f * 600 + k - 4];
            }
            hv[j] = (_Float16)v;
        }
        *reinterpret_cast<half8*>(Bp2 + (long)u * 8) = hv;
    } else if (u < 60800) {
        // Bc[m][ntg][lane][8]; k=m/10; kk=(m%10)*32+(lane>>4)*8+j; o=ntg*16+(lane&15)
        int v = u - 24320;
        int m = v / 1216, rest = v - m * 1216;
        int ntg = rest >> 6, lane = rest & 63;
        int o = ntg * 16 + (lane & 15);
        int kkb = (m % 10) * 32 + ((lane >> 4) << 3);
        int k = m / 10;
        half8 hv;
#pragma unroll
        for (int j = 0; j < 8; ++j) {
            int kk = kkb + j;
            float val = 0.f;
            if (o < 300 && kk < 300) val = conv_w[(o * 300 + kk) * 3 + k];
            hv[j] = (_Float16)val;
        }
        *reinterpret_cast<half8*>(Bc + (long)v * 8) = hv;
    } else if (u < 306560) {
        // X[(s,b,l)][i] = fp16(emb[q,i]), 320-padded
        int v = u - 60800;
        int g = v / 40;
        int e8 = (v - g * 40) * 8;
        int s = g / 3072;
        int rem = g - s * 3072;
        long row = (long)((s ? q2 : q1)[rem]) * 300;
        half8 hv;
        if (e8 + 7 < 300) {
            float4 a = *reinterpret_cast<const float4*>(emb + row + e8);
            float4 c = *reinterpret_cast<const float4*>(emb + row + e8 + 4);
            hv[0] = (_Float16)a.x; hv[1] = (_Float16)a.y; hv[2] = (_Float16)a.z; hv[3] = (_Float16)a.w;
            hv[4] = (_Float16)c.x; hv[5] = (_Float16)c.y; hv[6] = (_Float16)c.z; hv[7] = (_Float16)c.w;
        } else {
#pragma unroll
            for (int j = 0; j < 8; ++j) {
                int i = e8 + j;
                hv[j] = (_Float16)((i < 300) ? emb[row + i] : 0.f);
            }
        }
        *reinterpret_cast<half8*>(X + (long)g * XROW + e8) = hv;
    }
}

// ---------------- conv GEMM: one wave per (m-tile, ntg-pair) ----------------
__global__ __launch_bounds__(256, 4) void kc_conv(
    const _Float16* __restrict__ X, const _Float16* __restrict__ Bc,
    const float* __restrict__ conv_b, float* __restrict__ r1, float* __restrict__ r2)
{
    int wid = blockIdx.x * 4 + (threadIdx.x >> 6);   // 0..3839
    int lane = threadIdx.x & 63;
    int mt = wid / 10;            // m-tile 0..383
    int pr = wid - mt * 10;       // ntg-pair 0..9
    int ntg0 = pr * 2;
    bool two = (ntg0 + 1 < 19);
    int row0 = mt * 16;
    int q = lane >> 4, jcol = lane & 15;
    int grow = row0 + jcol;       // this lane's A row
    int l = grow % 48;

    auto zero8 = []() { half8 z; for (int e = 0; e < 8; ++e) z[e] = (_Float16)0.f; return z; };
    auto loadA = [&](int m) -> half8 {
        int k = m / 10, kk0 = (m - k * 10) * 32;
        int srcl = l + k - 1;
        if (srcl >= 0 && srcl < 48)
            return *reinterpret_cast<const half8*>(X + (long)(grow + k - 1) * XROW + kk0 + q * 8);
        return zero8();
    };
    auto loadB = [&](int m, int ntg) -> half8 {
        return *reinterpret_cast<const half8*>(Bc + ((long)m * 19 + ntg) * 512 + lane * 8);
    };

    float4v acc0 = (float4v){0.f, 0.f, 0.f, 0.f};
    float4v acc1 = (float4v){0.f, 0.f, 0.f, 0.f};

    half8 a_c  = loadA(0);
    half8 b0_c = loadB(0, ntg0);
    half8 b1_c = two ? loadB(0, ntg0 + 1) : b0_c;

    for (int m = 0; m < 30; ++m) {
        half8 a_n, b0_n, b1_n;
        if (m < 29) {
            a_n  = loadA(m + 1);
            b0_n = loadB(m + 1, ntg0);
            b1_n = two ? loadB(m + 1, ntg0 + 1) : b0_n;
        } else { a_n = a_c; b0_n = b0_c; b1_n = b1_c; }
        acc0 = __builtin_amdgcn_mfma_f32_16x16x32_f16(a_c, b0_c, acc0, 0, 0, 0);
        if (two)
            acc1 = __builtin_amdgcn_mfma_f32_16x16x32_f16(a_c, b1_c, acc1, 0, 0, 0);
        a_c = a_n; b0_c = b0_n; b1_c = b1_n;
    }

#pragma unroll
    for (int t = 0; t < 2; ++t) {
        if (t == 1 && !two) break;
        int n = (ntg0 + t) * 16 + jcol;
        if (n >= 300) continue;
        float bias = conv_b[n];
        const float4v& a = t ? acc1 : acc0;
#pragma unroll
        for (int r = 0; r < 4; ++r) {
            int g = row0 + q * 4 + r;
            int s = g / 3072;
            int rem = g - s * 3072;
            float* rout = s ? r2 : r1;
            rout[(long)rem * 300 + n] = tanhf(a[r] + bias);
        }
    }
}

// ---------------------------------------------------------------------------
// K2: barrier-free K-loop. Block = (b, it, jt, nc): 16i x 16j pairs, 64 f.
// ---------------------------------------------------------------------------
__global__ __launch_bounds__(256, 3) void k2_joint(
    const float* __restrict__ r1, const float* __restrict__ r2,
    const int* __restrict__ q1_len, const int* __restrict__ q2_len,
    const _Float16* __restrict__ Bp2,
    float* __restrict__ s1p, float* __restrict__ s2p)
{
    int x = blockIdx.x;               // 0..44
    int tile = x / 5, nc = x - tile * 5;
    int it = tile / 3, jt = tile - it * 3;
    int b = blockIdx.y;
    int tid = threadIdx.x;
    int q1l = q1_len[b], q2l = q2_len[b];
    long base1 = ((long)(b * 3 + jt) * 48 + it * 16) * 300;
    long base2 = ((long)(b * 3 + it) * 48 + jt * 16) * 300;
    bool active = (it * 16 < q1l) && (jt * 16 < q2l);
    if (!active) {
        for (int idx = tid; idx < 2048; idx += 256) {
            int side = idx >> 10;
            int rest = idx & 1023;
            int row = rest >> 6;
            int f = nc * 64 + (rest & 63);
            if (f < 300) (side ? s2p + base2 : s1p + base1)[row * 300 + f] = NEGP;
        }
        return;
    }

    __shared__ __align__(16) unsigned char smraw[16 * RS * 2 * 2];  // 19968 B
    _Float16* r1h = (_Float16*)smraw;
    _Float16* r2h = r1h + 16 * RS;
    float* red = (float*)smraw;       // union, epilogue only (64x68)

    {
        const float* r1base = r1 + ((long)(b * 48) + it * 16) * 300;
        const float* r2base = r2 + ((long)(b * 48) + jt * 16) * 300;
        for (int u = tid; u < 1200; u += 256) {
            int row = u / 75;
            int e4 = (u - row * 75) * 4;
            float4 v1 = *reinterpret_cast<const float4*>(r1base + row * 300 + e4);
            float4 v2 = *reinterpret_cast<const float4*>(r2base + row * 300 + e4);
            _Float16* d1 = r1h + row * RS + e4;
            _Float16* d2 = r2h + row * RS + e4;
            d1[0] = (_Float16)v1.x; d1[1] = (_Float16)v1.y; d1[2] = (_Float16)v1.z; d1[3] = (_Float16)v1.w;
            d2[0] = (_Float16)v2.x; d2[1] = (_Float16)v2.y; d2[2] = (_Float16)v2.z; d2[3] = (_Float16)v2.w;
        }
        for (int u = tid; u < 2 * 16 * (RS - 300); u += 256) {
            int half = u / (16 * (RS - 300));
            int rest = u - half * 16 * (RS - 300);
            int row = rest / (RS - 300);
            int e = 300 + rest - row * (RS - 300);
            (half ? r2h : r1h)[row * RS + e] = (_Float16)0.f;
        }
    }
    __syncthreads();

    int w    = tid >> 6;
    int lane = tid & 63;
    int q    = lane >> 4;
    int jcol = lane & 15;

    float4v acc[4][4];
#pragma unroll
    for (int mt = 0; mt < 4; ++mt)
#pragma unroll
        for (int nt = 0; nt < 4; ++nt) acc[mt][nt] = (float4v){0.f, 0.f, 0.f, 0.f};

    const _Float16* bbase = Bp2 + (long)(nc * 19) * 2048;
    half8 b0 = *reinterpret_cast<const half8*>(bbase + lane * 8);
    half8 b1 = *reinterpret_cast<const half8*>(bbase + 512 + lane * 8);
    half8 b2 = *reinterpret_cast<const half8*>(bbase + 1024 + lane * 8);
    half8 b3 = *reinterpret_cast<const half8*>(bbase + 1536 + lane * 8);

    for (int kc = 0; kc < 19; ++kc) {
        half8 n0, n1, n2, n3;
        if (kc < 18) {
            const _Float16* nb = bbase + (long)(kc + 1) * 2048;
            n0 = *reinterpret_cast<const half8*>(nb + lane * 8);
            n1 = *reinterpret_cast<const half8*>(nb + 512 + lane * 8);
            n2 = *reinterpret_cast<const half8*>(nb + 1024 + lane * 8);
            n3 = *reinterpret_cast<const half8*>(nb + 1536 + lane * 8);
        } else { n0 = b0; n1 = b1; n2 = b2; n3 = b3; }

        int k0q = kc * 32 + q * 8;
        int koff = (k0q < 304) ? k0q : (k0q - 304);
        const half8 rv2 = *reinterpret_cast<const half8*>(r2h + jcol * RS + koff);
        half8 afr[4];
#pragma unroll
        for (int mt = 0; mt < 4; ++mt) {
            const half8 rv1 = *reinterpret_cast<const half8*>(r1h + (w * 4 + mt) * RS + koff);
            if (k0q < 304) {
                half8 dsub = rv1 - rv2;
                short8 s;
                __builtin_memcpy(&s, &dsub, 16);
                s &= (short)0x7FFF;
                __builtin_memcpy(&afr[mt], &s, 16);
            } else {
                afr[mt] = rv1 * rv2;
            }
        }
#pragma unroll
        for (int mt = 0; mt < 4; ++mt) {
            acc[mt][0] = __builtin_amdgcn_mfma_f32_16x16x32_f16(afr[mt], b0, acc[mt][0], 0, 0, 0);
            acc[mt][1] = __builtin_amdgcn_mfma_f32_16x16x32_f16(afr[mt], b1, acc[mt][1], 0, 0, 0);
            acc[mt][2] = __builtin_amdgcn_mfma_f32_16x16x32_f16(afr[mt], b2, acc[mt][2], 0, 0, 0);
            acc[mt][3] = __builtin_amdgcn_mfma_f32_16x16x32_f16(afr[mt], b3, acc[mt][3], 0, 0, 0);
        }
        b0 = n0; b1 = n1; b2 = n2; b3 = n3;
    }

    // ---- s1: max over valid j ----
#pragma unroll
    for (int mt = 0; mt < 4; ++mt) {
        int i_l = w * 4 + mt;
#pragma unroll
        for (int nt = 0; nt < 4; ++nt) {
            float mx = NEGP;
#pragma unroll
            for (int r = 0; r < 4; ++r) {
                int j = q * 4 + r;
                if (jt * 16 + j < q2l) mx = fmaxf(mx, acc[mt][nt][r]);
            }
            mx = fmaxf(mx, __shfl_xor(mx, 16));
            mx = fmaxf(mx, __shfl_xor(mx, 32));
            int f = nc * 64 + nt * 16 + jcol;
            if (q == 0 && f < 300) s1p[base1 + i_l * 300 + f] = mx;
        }
    }

    // ---- s2: max over valid i, cross-wave via LDS ----
    __syncthreads();
#pragma unroll
    for (int nt = 0; nt < 4; ++nt) {
#pragma unroll
        for (int r = 0; r < 4; ++r) {
            float mx = NEGP;
#pragma unroll
            for (int mt = 0; mt < 4; ++mt) {
                int i = it * 16 + w * 4 + mt;
                if (i < q1l) mx = fmaxf(mx, acc[mt][nt][r]);
            }
            red[((w * 16) + q * 4 + r) * 68 + nt * 16 + jcol] = mx;
        }
    }
    __syncthreads();
    for (int vv = tid; vv < 1024; vv += 256) {
        int j = vv >> 6;
        int fcol = vv & 63;
        float mx = red[j * 68 + fcol];
        mx = fmaxf(mx, red[(16 + j) * 68 + fcol]);
        mx = fmaxf(mx, red[(32 + j) * 68 + fcol]);
        mx = fmaxf(mx, red[(48 + j) * 68 + fcol]);
        int f = nc * 64 + fcol;
        if (f < 300) s2p[base2 + (long)j * 300 + f] = mx;
    }
}

// K4: per (side,b): build s-tile in LDS (max3+bias+tanh), logits, softmax, pool.
// Replaces old k3_combine + pooling phases. Writes hcat[b*600 + side*300 + f].
__global__ __launch_bounds__(256) void k4_pool(
    const float* __restrict__ r1, const float* __restrict__ r2,
    const float* __restrict__ s1p, const float* __restrict__ s2p,
    const float* __restrict__ fc0b,
    const int* __restrict__ q1_len, const int* __restrict__ q2_len,
    const float* __restrict__ att_w, const float* __restrict__ att_b,
    float* __restrict__ hcat)
{
    int side = blockIdx.x >> 6;
    int b = blockIdx.x & 63;
    const float* r  = (side ? r2 : r1) + (long)b * 48 * 300;
    const float* sp = (side ? s2p : s1p) + (long)b * 43200;
    int len = (side ? q2_len : q1_len)[b];
    int tid = threadIdx.x;
    int w = tid >> 6, lane = tid & 63;
    __shared__ float sL[48 * 304];
    __shared__ float lg[48];
    __shared__ float aL[48];

    // phase 0: s tile = tanh(bias + max over 3 partials)
    for (int u = tid; u < 14400; u += 256) {
        int l = u / 300, f = u - l * 300;
        float mx = fmaxf(fmaxf(sp[u], sp[u + 14400]), sp[u + 28800]);
        sL[l * 304 + f] = tanhf(mx + fc0b[f]);
    }
    __syncthreads();

    // phase 1: logits (wave w owns l = w*12..w*12+11)
    for (int li = 0; li < 12; ++li) {
        int l = w * 12 + li;
        float acc = 0.f;
        for (int d = lane; d < 600; d += 64) {
            float v = (d < 300) ? r[l * 300 + d] : sL[l * 304 + d - 300];
            acc += v * att_w[d];
        }
#pragma unroll
        for (int off = 32; off >= 1; off >>= 1) acc += __shfl_xor(acc, off);
        if (lane == 0) lg[l] = acc + att_b[0];
    }
    __syncthreads();

    // phase 2: softmax (wave 0)
    if (tid < 64) {
        float lo = (lane < 48) ? lg[lane] : NEGP;
        float ml = (lane < len) ? lo : NEGP;
        float mx = ml;
#pragma unroll
        for (int off = 32; off >= 1; off >>= 1) mx = fmaxf(mx, __shfl_xor(mx, off));
        float ex = (lane < len) ? __expf(lo - mx) : 0.f;
        float sm = ex;
#pragma unroll
        for (int off = 32; off >= 1; off >>= 1) sm += __shfl_xor(sm, off);
        if (lane < 48) aL[lane] = ex / sm;
    }
    __syncthreads();

    // phase 3: pooled h from LDS
    for (int f = tid; f < 300; f += 256) {
        float acc = 0.f;
        for (int l = 0; l < 48; ++l) acc += aL[l] * sL[l * 304 + f];
        hcat[b * 600 + side * 300 + f] = acc;
    }
}

// K5a: fc1 — one wave per output (b,g); coalesced fp32 dot + shuffle reduce.
__global__ __launch_bounds__(256) void k5a_fc1(
    const float* __restrict__ hcat, const float* __restrict__ fc1w,
    const float* __restrict__ fc1b, float* __restrict__ jl)
{
    int wid = blockIdx.x * 4 + (threadIdx.x >> 6);   // 0..19199
    int lane = threadIdx.x & 63;
    int b = wid / 300;
    int g = wid - b * 300;
    const float* h = hcat + (long)b * 600;
    const float* wrow = fc1w + (long)g * 600;
    float acc = 0.f;
    for (int e = lane; e < 600; e += 64)
        acc += h[e] * wrow[e];
#pragma unroll
    for (int off = 32; off >= 1; off >>= 1) acc += __shfl_xor(acc, off);
    if (lane == 0) jl[b * 300 + g] = tanhf(acc + fc1b[g]);
}

// K5b: fc2 — one block per b, wave per output class.
__global__ __launch_bounds__(128) void k5b_fc2(
    const float* __restrict__ jl, const float* __restrict__ fc2w,
    const float* __restrict__ fc2b, float* __restrict__ out)
{
    int b = blockIdx.x;
    int o = threadIdx.x >> 6, lane = threadIdx.x & 63;
    float acc = 0.f;
    for (int g = lane; g < 300; g += 64)
        acc += jl[b * 300 + g] * fc2w[o * 300 + g];
#pragma unroll
    for (int off = 32; off >= 1; off >>= 1) acc += __shfl_xor(acc, off);
    if (lane == 0) out[b * 2 + o] = acc + fc2b[o];
}

extern "C" void kernel_launch(void* const* d_in, const int* in_sizes, int n_in,
                              void* d_out, int out_size, void* d_ws, size_t ws_size,
                              hipStream_t stream)
{
    const int*   q1     = (const int*)d_in[0];
    const int*   q2     = (const int*)d_in[1];
    const int*   q1_len = (const int*)d_in[2];
    const int*   q2_len = (const int*)d_in[3];
    const float* emb    = (const float*)d_in[4];
    const float* conv_w = (const float*)d_in[5];
    const float* conv_b = (const float*)d_in[6];
    const float* fc0_w  = (const float*)d_in[7];
    const float* fc0_b  = (const float*)d_in[8];
    const float* fc1_w  = (const float*)d_in[9];
    const float* fc1_b  = (const float*)d_in[10];
    const float* fc2_w  = (const float*)d_in[11];
    const float* fc2_b  = (const float*)d_in[12];
    const float* att_w  = (const float*)d_in[13];
    const float* att_b  = (const float*)d_in[14];

    float* ws  = (float*)d_ws;
    float* r1  = ws;
    float* r2  = ws + 921600;
    float* s1p = ws + 1843200;
    float* s2p = ws + 4608000;
    float* hcat = ws + 9216000;
    float* jl   = ws + 9351680;
    _Float16* X   = (_Float16*)(ws + 1843200);   // pre-k2 alias of s1p region
    _Float16* Bc  = (_Float16*)(ws + 2826240);   // pre-k2 alias of s1p region
    _Float16* Bp2 = (_Float16*)(ws + 9254400);
    float* out = (float*)d_out;

    hipLaunchKernelGGL(kp_all, dim3(1198), dim3(256), 0, stream,
                       q1, q2, emb, conv_w, fc0_w, Bp2, Bc, X);
    hipLaunchKernelGGL(kc_conv, dim3(960), dim3(256), 0, stream,
                       X, Bc, conv_b, r1, r2);
    hipLaunchKernelGGL(k2_joint, dim3(45, 64), dim3(256), 0, stream,
                       r1, r2, q1_len, q2_len, Bp2, s1p, s2p);
    hipLaunchKernelGGL(k4_pool, dim3(128), dim3(256), 0, stream,
                       r1, r2, s1p, s2p, fc0_b, q1_len, q2_len, att_w, att_b, hcat);
    hipLaunchKernelGGL(k5a_fc1, dim3(4800), dim3(256), 0, stream,
                       hcat, fc1_w, fc1_b, jl);
    hipLaunchKernelGGL(k5b_fc2, dim3(64), dim3(128), 0, stream,
                       jl, fc2_w, fc2_b, out);
}

// Round 8
// 217.908 us; speedup vs baseline: 1.3348x; 1.1370x over previous
//
#include <hip/hip_runtime.h>
#include <math.h>

#define B_  64
#define L_  48
#define E_  300
#define F0_ 300
#define NEGP (-1e30f)
#define XROW 320      // X row stride in halves (640B, 16B aligned)
#define RS  312       // k2 r-tile LDS row stride (halves)

typedef __attribute__((ext_vector_type(8))) _Float16 half8;
typedef __attribute__((ext_vector_type(8))) short   short8;
typedef __attribute__((ext_vector_type(4))) float   float4v;

// -------- workspace layout (float offsets) --------
// r1    : 0        .. 921600      (B*L*E) fp32
// r2    : 921600   .. 1843200
// s1p   : 1843200  .. 4608000     (B*3*48*300) pre-tanh partial max over j per j-tile
//   X   : 1843200  .. 2826240     [pre-k2 alias] 6144x320 fp16 gathered embeddings
//   Bc  : 2826240  .. 2972160     [pre-k2 alias] 30x19x64x8 fp16 conv-W frags
// s2p   : 4608000  .. 7372800
// sg1   : 7372800  .. 8294400     combined s1 (tanh'd)
// sg2   : 8294400  .. 9216000     combined s2
// hcat  : 9216000  .. 9254400     64x600 pooled features
// Bp2   : 9254400  .. 9351680     95x4x64x8 fp16 fc0_w frags (per-lane order)
// jl    : 9351680  .. 9370880     64x300 fc1 activations
// lg    : 9370880  .. 9377024     2x64x48 attention logits

// ---------------- fused prep kernel ----------------
// sections (half8 units): Bp2 24320 | Bc 36480 | X 245760  -> total 306560
__global__ __launch_bounds__(256) void kp_all(
    const int* __restrict__ q1, const int* __restrict__ q2,
    const float* __restrict__ emb, const float* __restrict__ conv_w,
    const float* __restrict__ fc0w,
    _Float16* __restrict__ Bp2, _Float16* __restrict__ Bc,
    _Float16* __restrict__ X)
{
    int u = blockIdx.x * 256 + threadIdx.x;
    if (u < 24320) {
        // Bp2[m][nt][lane][8]; m=nc*19+kc; f=nc*64+nt*16+(lane&15); k=kc*32+(lane>>4)*8+j
        int m = u >> 8, rest = u & 255;
        int nt = rest >> 6, lane = rest & 63;
        int f = (m / 19) * 64 + nt * 16 + (lane & 15);
        int kb = (m % 19) * 32 + ((lane >> 4) << 3);
        half8 hv;
#pragma unroll
        for (int j = 0; j < 8; ++j) {
            int k = kb + j;
            float v = 0.f;
            if (f < 300) {
                if (k < 300) v = fc0w[f * 600 + k];
                else if (k >= 304 && k < 604) v = fc0w[f * 600 + k - 4];
            }
            hv[j] = (_Float16)v;
        }
        *reinterpret_cast<half8*>(Bp2 + (long)u * 8) = hv;
    } else if (u < 60800) {
        // Bc[m][ntg][lane][8]; k=m/10; kk=(m%10)*32+(lane>>4)*8+j; o=ntg*16+(lane&15)
        int v = u - 24320;
        int m = v / 1216, rest = v - m * 1216;
        int ntg = rest >> 6, lane = rest & 63;
        int o = ntg * 16 + (lane & 15);
        int kkb = (m % 10) * 32 + ((lane >> 4) << 3);
        int k = m / 10;
        half8 hv;
#pragma unroll
        for (int j = 0; j < 8; ++j) {
            int kk = kkb + j;
            float val = 0.f;
            if (o < 300 && kk < 300) val = conv_w[(o * 300 + kk) * 3 + k];
            hv[j] = (_Float16)val;
        }
        *reinterpret_cast<half8*>(Bc + (long)v * 8) = hv;
    } else if (u < 306560) {
        // X[(s,b,l)][i] = fp16(emb[q,i]), 320-padded
        int v = u - 60800;
        int g = v / 40;
        int e8 = (v - g * 40) * 8;
        int s = g / 3072;
        int rem = g - s * 3072;
        long row = (long)((s ? q2 : q1)[rem]) * 300;
        half8 hv;
        if (e8 + 7 < 300) {
            float4 a = *reinterpret_cast<const float4*>(emb + row + e8);
            float4 c = *reinterpret_cast<const float4*>(emb + row + e8 + 4);
            hv[0] = (_Float16)a.x; hv[1] = (_Float16)a.y; hv[2] = (_Float16)a.z; hv[3] = (_Float16)a.w;
            hv[4] = (_Float16)c.x; hv[5] = (_Float16)c.y; hv[6] = (_Float16)c.z; hv[7] = (_Float16)c.w;
        } else {
#pragma unroll
            for (int j = 0; j < 8; ++j) {
                int i = e8 + j;
                hv[j] = (_Float16)((i < 300) ? emb[row + i] : 0.f);
            }
        }
        *reinterpret_cast<half8*>(X + (long)g * XROW + e8) = hv;
    }
}

// ---------------- conv GEMM: one wave per (m-tile, ntg-pair) ----------------
__global__ __launch_bounds__(256, 4) void kc_conv(
    const _Float16* __restrict__ X, const _Float16* __restrict__ Bc,
    const float* __restrict__ conv_b, float* __restrict__ r1, float* __restrict__ r2)
{
    int wid = blockIdx.x * 4 + (threadIdx.x >> 6);   // 0..3839
    int lane = threadIdx.x & 63;
    int mt = wid / 10;            // m-tile 0..383
    int pr = wid - mt * 10;       // ntg-pair 0..9
    int ntg0 = pr * 2;
    bool two = (ntg0 + 1 < 19);
    int row0 = mt * 16;
    int q = lane >> 4, jcol = lane & 15;
    int grow = row0 + jcol;       // this lane's A row
    int l = grow % 48;

    auto zero8 = []() { half8 z; for (int e = 0; e < 8; ++e) z[e] = (_Float16)0.f; return z; };
    auto loadA = [&](int m) -> half8 {
        int k = m / 10, kk0 = (m - k * 10) * 32;
        int srcl = l + k - 1;
        if (srcl >= 0 && srcl < 48)
            return *reinterpret_cast<const half8*>(X + (long)(grow + k - 1) * XROW + kk0 + q * 8);
        return zero8();
    };
    auto loadB = [&](int m, int ntg) -> half8 {
        return *reinterpret_cast<const half8*>(Bc + ((long)m * 19 + ntg) * 512 + lane * 8);
    };

    float4v acc0 = (float4v){0.f, 0.f, 0.f, 0.f};
    float4v acc1 = (float4v){0.f, 0.f, 0.f, 0.f};

    half8 a_c  = loadA(0);
    half8 b0_c = loadB(0, ntg0);
    half8 b1_c = two ? loadB(0, ntg0 + 1) : b0_c;

    for (int m = 0; m < 30; ++m) {
        half8 a_n, b0_n, b1_n;
        if (m < 29) {
            a_n  = loadA(m + 1);
            b0_n = loadB(m + 1, ntg0);
            b1_n = two ? loadB(m + 1, ntg0 + 1) : b0_n;
        } else { a_n = a_c; b0_n = b0_c; b1_n = b1_c; }
        acc0 = __builtin_amdgcn_mfma_f32_16x16x32_f16(a_c, b0_c, acc0, 0, 0, 0);
        if (two)
            acc1 = __builtin_amdgcn_mfma_f32_16x16x32_f16(a_c, b1_c, acc1, 0, 0, 0);
        a_c = a_n; b0_c = b0_n; b1_c = b1_n;
    }

#pragma unroll
    for (int t = 0; t < 2; ++t) {
        if (t == 1 && !two) break;
        int n = (ntg0 + t) * 16 + jcol;
        if (n >= 300) continue;
        float bias = conv_b[n];
        const float4v& a = t ? acc1 : acc0;
#pragma unroll
        for (int r = 0; r < 4; ++r) {
            int g = row0 + q * 4 + r;
            int s = g / 3072;
            int rem = g - s * 3072;
            float* rout = s ? r2 : r1;
            rout[(long)rem * 300 + n] = tanhf(a[r] + bias);
        }
    }
}

// ---------------------------------------------------------------------------
// K2: barrier-free K-loop. Block = (b, it, jt, nc): 16i x 16j pairs, 64 f.
// ---------------------------------------------------------------------------
__global__ __launch_bounds__(256, 3) void k2_joint(
    const float* __restrict__ r1, const float* __restrict__ r2,
    const int* __restrict__ q1_len, const int* __restrict__ q2_len,
    const _Float16* __restrict__ Bp2,
    float* __restrict__ s1p, float* __restrict__ s2p)
{
    int x = blockIdx.x;               // 0..44
    int tile = x / 5, nc = x - tile * 5;
    int it = tile / 3, jt = tile - it * 3;
    int b = blockIdx.y;
    int tid = threadIdx.x;
    int q1l = q1_len[b], q2l = q2_len[b];
    long base1 = ((long)(b * 3 + jt) * 48 + it * 16) * 300;
    long base2 = ((long)(b * 3 + it) * 48 + jt * 16) * 300;
    bool active = (it * 16 < q1l) && (jt * 16 < q2l);
    if (!active) {
        for (int idx = tid; idx < 2048; idx += 256) {
            int side = idx >> 10;
            int rest = idx & 1023;
            int row = rest >> 6;
            int f = nc * 64 + (rest & 63);
            if (f < 300) (side ? s2p + base2 : s1p + base1)[row * 300 + f] = NEGP;
        }
        return;
    }

    __shared__ __align__(16) unsigned char smraw[16 * RS * 2 * 2];  // 19968 B
    _Float16* r1h = (_Float16*)smraw;
    _Float16* r2h = r1h + 16 * RS;
    float* red = (float*)smraw;       // union, epilogue only (64x68)

    {
        const float* r1base = r1 + ((long)(b * 48) + it * 16) * 300;
        const float* r2base = r2 + ((long)(b * 48) + jt * 16) * 300;
        for (int u = tid; u < 1200; u += 256) {
            int row = u / 75;
            int e4 = (u - row * 75) * 4;
            float4 v1 = *reinterpret_cast<const float4*>(r1base + row * 300 + e4);
            float4 v2 = *reinterpret_cast<const float4*>(r2base + row * 300 + e4);
            _Float16* d1 = r1h + row * RS + e4;
            _Float16* d2 = r2h + row * RS + e4;
            d1[0] = (_Float16)v1.x; d1[1] = (_Float16)v1.y; d1[2] = (_Float16)v1.z; d1[3] = (_Float16)v1.w;
            d2[0] = (_Float16)v2.x; d2[1] = (_Float16)v2.y; d2[2] = (_Float16)v2.z; d2[3] = (_Float16)v2.w;
        }
        for (int u = tid; u < 2 * 16 * (RS - 300); u += 256) {
            int half = u / (16 * (RS - 300));
            int rest = u - half * 16 * (RS - 300);
            int row = rest / (RS - 300);
            int e = 300 + rest - row * (RS - 300);
            (half ? r2h : r1h)[row * RS + e] = (_Float16)0.f;
        }
    }
    __syncthreads();

    int w    = tid >> 6;
    int lane = tid & 63;
    int q    = lane >> 4;
    int jcol = lane & 15;

    float4v acc[4][4];
#pragma unroll
    for (int mt = 0; mt < 4; ++mt)
#pragma unroll
        for (int nt = 0; nt < 4; ++nt) acc[mt][nt] = (float4v){0.f, 0.f, 0.f, 0.f};

    const _Float16* bbase = Bp2 + (long)(nc * 19) * 2048;
    half8 b0 = *reinterpret_cast<const half8*>(bbase + lane * 8);
    half8 b1 = *reinterpret_cast<const half8*>(bbase + 512 + lane * 8);
    half8 b2 = *reinterpret_cast<const half8*>(bbase + 1024 + lane * 8);
    half8 b3 = *reinterpret_cast<const half8*>(bbase + 1536 + lane * 8);

    for (int kc = 0; kc < 19; ++kc) {
        half8 n0, n1, n2, n3;
        if (kc < 18) {
            const _Float16* nb = bbase + (long)(kc + 1) * 2048;
            n0 = *reinterpret_cast<const half8*>(nb + lane * 8);
            n1 = *reinterpret_cast<const half8*>(nb + 512 + lane * 8);
            n2 = *reinterpret_cast<const half8*>(nb + 1024 + lane * 8);
            n3 = *reinterpret_cast<const half8*>(nb + 1536 + lane * 8);
        } else { n0 = b0; n1 = b1; n2 = b2; n3 = b3; }

        int k0q = kc * 32 + q * 8;
        int koff = (k0q < 304) ? k0q : (k0q - 304);
        const half8 rv2 = *reinterpret_cast<const half8*>(r2h + jcol * RS + koff);
        half8 afr[4];
#pragma unroll
        for (int mt = 0; mt < 4; ++mt) {
            const half8 rv1 = *reinterpret_cast<const half8*>(r1h + (w * 4 + mt) * RS + koff);
            if (k0q < 304) {
                half8 dsub = rv1 - rv2;
                short8 s;
                __builtin_memcpy(&s, &dsub, 16);
                s &= (short)0x7FFF;
                __builtin_memcpy(&afr[mt], &s, 16);
            } else {
                afr[mt] = rv1 * rv2;
            }
        }
#pragma unroll
        for (int mt = 0; mt < 4; ++mt) {
            acc[mt][0] = __builtin_amdgcn_mfma_f32_16x16x32_f16(afr[mt], b0, acc[mt][0], 0, 0, 0);
            acc[mt][1] = __builtin_amdgcn_mfma_f32_16x16x32_f16(afr[mt], b1, acc[mt][1], 0, 0, 0);
            acc[mt][2] = __builtin_amdgcn_mfma_f32_16x16x32_f16(afr[mt], b2, acc[mt][2], 0, 0, 0);
            acc[mt][3] = __builtin_amdgcn_mfma_f32_16x16x32_f16(afr[mt], b3, acc[mt][3], 0, 0, 0);
        }
        b0 = n0; b1 = n1; b2 = n2; b3 = n3;
    }

    // ---- s1: max over valid j ----
#pragma unroll
    for (int mt = 0; mt < 4; ++mt) {
        int i_l = w * 4 + mt;
#pragma unroll
        for (int nt = 0; nt < 4; ++nt) {
            float mx = NEGP;
#pragma unroll
            for (int r = 0; r < 4; ++r) {
                int j = q * 4 + r;
                if (jt * 16 + j < q2l) mx = fmaxf(mx, acc[mt][nt][r]);
            }
            mx = fmaxf(mx, __shfl_xor(mx, 16));
            mx = fmaxf(mx, __shfl_xor(mx, 32));
            int f = nc * 64 + nt * 16 + jcol;
            if (q == 0 && f < 300) s1p[base1 + i_l * 300 + f] = mx;
        }
    }

    // ---- s2: max over valid i, cross-wave via LDS ----
    __syncthreads();
#pragma unroll
    for (int nt = 0; nt < 4; ++nt) {
#pragma unroll
        for (int r = 0; r < 4; ++r) {
            float mx = NEGP;
#pragma unroll
            for (int mt = 0; mt < 4; ++mt) {
                int i = it * 16 + w * 4 + mt;
                if (i < q1l) mx = fmaxf(mx, acc[mt][nt][r]);
            }
            red[((w * 16) + q * 4 + r) * 68 + nt * 16 + jcol] = mx;
        }
    }
    __syncthreads();
    for (int vv = tid; vv < 1024; vv += 256) {
        int j = vv >> 6;
        int fcol = vv & 63;
        float mx = red[j * 68 + fcol];
        mx = fmaxf(mx, red[(16 + j) * 68 + fcol]);
        mx = fmaxf(mx, red[(32 + j) * 68 + fcol]);
        mx = fmaxf(mx, red[(48 + j) * 68 + fcol]);
        int f = nc * 64 + fcol;
        if (f < 300) s2p[base2 + (long)j * 300 + f] = mx;
    }
}

// K3a: one wave per (side,b,l): s = tanh(bias + max3), write sg, compute logit.
__global__ __launch_bounds__(256) void k3a_comb(
    const float* __restrict__ r1, const float* __restrict__ r2,
    const float* __restrict__ s1p, const float* __restrict__ s2p,
    const float* __restrict__ fc0b,
    const float* __restrict__ att_w, const float* __restrict__ att_b,
    float* __restrict__ sg1, float* __restrict__ sg2,
    float* __restrict__ lg)
{
    int wid = blockIdx.x * 4 + (threadIdx.x >> 6);   // 0..6143
    int lane = threadIdx.x & 63;
    int side = wid / 3072;
    int rem = wid - side * 3072;                     // b*48 + l
    int b = rem / 48, l = rem - b * 48;
    const float* sp = (side ? s2p : s1p) + (long)b * 43200 + l * 300;
    const float* r  = (side ? r2 : r1) + (long)rem * 300;
    float* sg = (side ? sg2 : sg1) + (long)rem * 300;

    float lacc = 0.f;
    for (int e = lane; e < 300; e += 64) {
        float mx = fmaxf(fmaxf(sp[e], sp[e + 14400]), sp[e + 28800]);
        float s = tanhf(mx + fc0b[e]);
        sg[e] = s;
        lacc += s * att_w[300 + e] + r[e] * att_w[e];
    }
#pragma unroll
    for (int off = 32; off >= 1; off >>= 1) lacc += __shfl_xor(lacc, off);
    if (lane == 0) lg[wid] = lacc + att_b[0];
}

// K4p: one wave per (side,b,f-chunk of 60): in-register softmax + pool.
__global__ __launch_bounds__(64) void k4p_pool(
    const float* __restrict__ sg1, const float* __restrict__ sg2,
    const float* __restrict__ lg,
    const int* __restrict__ q1_len, const int* __restrict__ q2_len,
    float* __restrict__ hcat)
{
    int bid = blockIdx.x;             // ((side*64)+b)*5 + fc
    int side = bid / 320;
    int rest = bid - side * 320;
    int b = rest / 5, fc = rest - b * 5;
    int lane = threadIdx.x;
    int len = (side ? q2_len : q1_len)[b];
    const float* sg = (side ? sg2 : sg1) + (long)b * 48 * 300;

    // softmax over 48 logits, aL held in lane l (l<48)
    float lo = (lane < 48) ? lg[(side * 64 + b) * 48 + lane] : NEGP;
    float ml = (lane < len) ? lo : NEGP;
    float mx = ml;
#pragma unroll
    for (int off = 32; off >= 1; off >>= 1) mx = fmaxf(mx, __shfl_xor(mx, off));
    float ex = (lane < len) ? __expf(lo - mx) : 0.f;
    float sm = ex;
#pragma unroll
    for (int off = 32; off >= 1; off >>= 1) sm += __shfl_xor(sm, off);
    float aLv = ex / sm;

    int f = fc * 60 + lane;
    float acc = 0.f;
    for (int l = 0; l < 48; ++l) {
        float a = __shfl(aLv, l);
        if (f < 300) acc += a * sg[(long)l * 300 + f];
    }
    if (f < 300 && lane < 60)
        hcat[b * 600 + side * 300 + f] = acc;
}

// K5a: fc1 — one wave per output (b,g); coalesced fp32 dot + shuffle reduce.
__global__ __launch_bounds__(256) void k5a_fc1(
    const float* __restrict__ hcat, const float* __restrict__ fc1w,
    const float* __restrict__ fc1b, float* __restrict__ jl)
{
    int wid = blockIdx.x * 4 + (threadIdx.x >> 6);   // 0..19199
    int lane = threadIdx.x & 63;
    int b = wid / 300;
    int g = wid - b * 300;
    const float* h = hcat + (long)b * 600;
    const float* wrow = fc1w + (long)g * 600;
    float acc = 0.f;
    for (int e = lane; e < 600; e += 64)
        acc += h[e] * wrow[e];
#pragma unroll
    for (int off = 32; off >= 1; off >>= 1) acc += __shfl_xor(acc, off);
    if (lane == 0) jl[b * 300 + g] = tanhf(acc + fc1b[g]);
}

// K5b: fc2 — one block per b, wave per output class.
__global__ __launch_bounds__(128) void k5b_fc2(
    const float* __restrict__ jl, const float* __restrict__ fc2w,
    const float* __restrict__ fc2b, float* __restrict__ out)
{
    int b = blockIdx.x;
    int o = threadIdx.x >> 6, lane = threadIdx.x & 63;
    float acc = 0.f;
    for (int g = lane; g < 300; g += 64)
        acc += jl[b * 300 + g] * fc2w[o * 300 + g];
#pragma unroll
    for (int off = 32; off >= 1; off >>= 1) acc += __shfl_xor(acc, off);
    if (lane == 0) out[b * 2 + o] = acc + fc2b[o];
}

extern "C" void kernel_launch(void* const* d_in, const int* in_sizes, int n_in,
                              void* d_out, int out_size, void* d_ws, size_t ws_size,
                              hipStream_t stream)
{
    const int*   q1     = (const int*)d_in[0];
    const int*   q2     = (const int*)d_in[1];
    const int*   q1_len = (const int*)d_in[2];
    const int*   q2_len = (const int*)d_in[3];
    const float* emb    = (const float*)d_in[4];
    const float* conv_w = (const float*)d_in[5];
    const float* conv_b = (const float*)d_in[6];
    const float* fc0_w  = (const float*)d_in[7];
    const float* fc0_b  = (const float*)d_in[8];
    const float* fc1_w  = (const float*)d_in[9];
    const float* fc1_b  = (const float*)d_in[10];
    const float* fc2_w  = (const float*)d_in[11];
    const float* fc2_b  = (const float*)d_in[12];
    const float* att_w  = (const float*)d_in[13];
    const float* att_b  = (const float*)d_in[14];

    float* ws  = (float*)d_ws;
    float* r1  = ws;
    float* r2  = ws + 921600;
    float* s1p = ws + 1843200;
    float* s2p = ws + 4608000;
    float* sg1 = ws + 7372800;
    float* sg2 = ws + 8294400;
    float* hcat = ws + 9216000;
    float* jl   = ws + 9351680;
    float* lg   = ws + 9370880;
    _Float16* X   = (_Float16*)(ws + 1843200);   // pre-k2 alias of s1p region
    _Float16* Bc  = (_Float16*)(ws + 2826240);   // pre-k2 alias of s1p region
    _Float16* Bp2 = (_Float16*)(ws + 9254400);
    float* out = (float*)d_out;

    hipLaunchKernelGGL(kp_all, dim3(1198), dim3(256), 0, stream,
                       q1, q2, emb, conv_w, fc0_w, Bp2, Bc, X);
    hipLaunchKernelGGL(kc_conv, dim3(960), dim3(256), 0, stream,
                       X, Bc, conv_b, r1, r2);
    hipLaunchKernelGGL(k2_joint, dim3(45, 64), dim3(256), 0, stream,
                       r1, r2, q1_len, q2_len, Bp2, s1p, s2p);
    hipLaunchKernelGGL(k3a_comb, dim3(1536), dim3(256), 0, stream,
                       r1, r2, s1p, s2p, fc0_b, att_w, att_b, sg1, sg2, lg);
    hipLaunchKernelGGL(k4p_pool, dim3(640), dim3(64), 0, stream,
                       sg1, sg2, lg, q1_len, q2_len, hcat);
    hipLaunchKernelGGL(k5a_fc1, dim3(4800), dim3(256), 0, stream,
                       hcat, fc1_w, fc1_b, jl);
    hipLaunchKernelGGL(k5b_fc2, dim3(64), dim3(128), 0, stream,
                       jl, fc2_w, fc2_b, out);
}